// Round 3
// baseline (419.434 us; speedup 1.0000x reference)
//
#include <hip/hip_runtime.h>
#include <cmath>

#define CTXL 50
#define NC 300    // NCOND
#define NH 256    // NHID
#define NT 256    // threads per block
#define KPAD 320  // K padded to 10 k-steps of 32
#define AROWS 50  // LDS A rows (m-tile 3 rows >=50 clamp to row 0, masked in pool)
#define ASTR 328  // A row stride in shorts (656 B -> avoids 16-way bank conflicts)

typedef float  f32x4 __attribute__((ext_vector_type(4)));
typedef short  s16x8 __attribute__((ext_vector_type(8)));

__device__ __forceinline__ ushort f2bf(float f) {
    unsigned u = __float_as_uint(f);
    unsigned r = (u + 0x7FFFu + ((u >> 16) & 1u)) >> 16;   // RNE
    return (ushort)r;
}
__device__ __forceinline__ float bf2f(ushort u) {
    return __uint_as_float(((unsigned)u) << 16);
}

// ---------------------------------------------------------------------------
// prepass A: embs [ntok][300] f32 -> E16 [ntok][320] bf16 (K zero-padded)
__global__ void convert_table(const float* __restrict__ embs,
                              ushort* __restrict__ E16, int ntok) {
    const int total = ntok * 40;               // 8-short chunks per row
    for (int g = blockIdx.x * blockDim.x + threadIdx.x; g < total;
         g += gridDim.x * blockDim.x) {
        const int row = g / 40;
        const int l   = g - row * 40;
        const float* src = embs + (size_t)row * NC + l * 8;
        float v[8];
        if (l < 37) {
            const float4 a = *(const float4*)src;
            const float4 c = *(const float4*)(src + 4);
            v[0]=a.x; v[1]=a.y; v[2]=a.z; v[3]=a.w;
            v[4]=c.x; v[5]=c.y; v[6]=c.z; v[7]=c.w;
        } else if (l == 37) {                  // floats 296..299 real, 300..303 pad
            const float4 a = *(const float4*)src;
            v[0]=a.x; v[1]=a.y; v[2]=a.z; v[3]=a.w;
            v[4]=v[5]=v[6]=v[7]=0.0f;
        } else {
            #pragma unroll
            for (int q = 0; q < 8; ++q) v[q] = 0.0f;
        }
        s16x8 p;
        #pragma unroll
        for (int q = 0; q < 8; ++q) p[q] = (short)f2bf(v[q]);
        *(s16x8*)(E16 + (size_t)row * KPAD + l * 8) = p;
    }
}

// ---------------------------------------------------------------------------
// prepass B: W1 [300][256] -> W1T bf16 [256][320]; W2 [256][300] -> W2T bf16 [300][256]
__global__ void convert_w(const float* __restrict__ W1, const float* __restrict__ W2,
                          ushort* __restrict__ W1T, ushort* __restrict__ W2T) {
    const int t  = threadIdx.x;
    const int bi = blockIdx.x;
    if (bi < KPAD) {                   // k = bi
        W1T[(size_t)t * KPAD + bi] = (bi < NC) ? f2bf(W1[(size_t)bi * NH + t]) : (ushort)0;
    } else {                           // j = bi - KPAD (< 300)
        const int j = bi - KPAD;
        W2T[(size_t)j * NH + t] = f2bf(W2[(size_t)t * NC + j]);
    }
}

// ---------------------------------------------------------------------------
// main: one block per batch element. 4 waves; wave w owns cols [64w,64w+64).
template <bool BF16SRC>
__global__ __launch_bounds__(NT, 4)
void esa_main(const int* __restrict__ x,
              const int* __restrict__ ctx,
              const float* __restrict__ embs,
              const float* __restrict__ b1,
              const float* __restrict__ b2,
              const ushort* __restrict__ E16,
              const ushort* __restrict__ W1T,
              const ushort* __restrict__ W2T,
              float* __restrict__ out) {
    __shared__ short A[AROWS * ASTR];      // 32800 B bf16 context tile (padded K)
    __shared__ float xemb[NC];             // 1200 B
    __shared__ float pooled[NH];           // 1024 B

    const int b    = blockIdx.x;
    const int tid  = threadIdx.x;
    const int wave = tid >> 6;
    const int lane = tid & 63;
    const int l15  = lane & 15;
    const int lhi  = lane >> 4;

    // -------- phase 1: gather 50 context rows -> LDS (one pass, 4 thr/row) --
    {
        const int r  = tid >> 2;           // 0..63
        const int cq = tid & 3;
        if (r < CTXL) {
            const int row = ctx[b * CTXL + r];
            if (BF16SRC) {
                const ushort* src = E16 + (size_t)row * KPAD;
                #pragma unroll
                for (int i = 0; i < 10; ++i) {
                    const int c = cq + 4 * i;          // 16B chunk 0..39
                    *(s16x8*)((char*)A + (size_t)r * (ASTR * 2) + c * 16) =
                        *(const s16x8*)(src + c * 8);
                }
            } else {
                const float* src = embs + (size_t)row * NC;
                #pragma unroll
                for (int i = 0; i < 19; ++i) {
                    const int c = cq + 4 * i;          // float4 chunk 0..74
                    if (c < 75) {
                        const float4 v = *(const float4*)(src + c * 4);
                        uint2 p;
                        p.x = (unsigned)f2bf(v.x) | ((unsigned)f2bf(v.y) << 16);
                        p.y = (unsigned)f2bf(v.z) | ((unsigned)f2bf(v.w) << 16);
                        *(uint2*)((char*)A + (size_t)r * (ASTR * 2) + c * 8) = p;
                    }
                }
                #pragma unroll
                for (int k = cq; k < 5; k += 4)        // zero shorts 300..319
                    *(uint2*)((char*)A + (size_t)r * (ASTR * 2) + 600 + k * 8) =
                        make_uint2(0u, 0u);
            }
        }
    }
    {   // x embedding row (fp32, kept full precision for the final multiply)
        const int row = x[b];
        if (tid < NC / 4)
            ((float4*)xemb)[tid] = ((const float4*)(embs + (size_t)row * NC))[tid];
    }

    // -------- phase 2: MFMA h = c_embs @ W1; relu+bias+mean fused ------------
    int abyte[4];
    #pragma unroll
    for (int mt = 0; mt < 4; ++mt) {
        int rr = mt * 16 + l15;
        if (rr >= CTXL) rr = 0;                 // clamped rows masked in pooling
        abyte[mt] = rr * (ASTR * 2) + lhi * 16;
    }
    const ushort* wb = W1T + (size_t)(wave * 64 + l15) * KPAD + lhi * 8;

    s16x8 bcur[4];                              // B prefetch issued BEFORE barrier
    #pragma unroll
    for (int nt = 0; nt < 4; ++nt)
        bcur[nt] = *(const s16x8*)(wb + nt * 16 * KPAD);

    __syncthreads();

    f32x4 acc[4][4];
    #pragma unroll
    for (int mt = 0; mt < 4; ++mt)
        #pragma unroll
        for (int nt = 0; nt < 4; ++nt)
            acc[mt][nt] = (f32x4){0.f, 0.f, 0.f, 0.f};

    #pragma unroll
    for (int ks = 0; ks < KPAD / 32; ++ks) {
        s16x8 af[4];
        #pragma unroll
        for (int mt = 0; mt < 4; ++mt)
            af[mt] = *(const s16x8*)((const char*)A + abyte[mt] + ks * 64);
        s16x8 bnx[4];
        if (ks < KPAD / 32 - 1) {
            #pragma unroll
            for (int nt = 0; nt < 4; ++nt)
                bnx[nt] = *(const s16x8*)(wb + nt * 16 * KPAD + (ks + 1) * 32);
        }
        #pragma unroll
        for (int mt = 0; mt < 4; ++mt)
            #pragma unroll
            for (int nt = 0; nt < 4; ++nt)
                acc[mt][nt] = __builtin_amdgcn_mfma_f32_16x16x32_bf16(
                    af[mt], bcur[nt], acc[mt][nt], 0, 0, 0);
        if (ks < KPAD / 32 - 1) {
            #pragma unroll
            for (int nt = 0; nt < 4; ++nt) bcur[nt] = bnx[nt];
        }
    }

    // relu(acc + b1), masked mean over rows < 50
    #pragma unroll
    for (int nt = 0; nt < 4; ++nt) {
        const float bb = b1[wave * 64 + nt * 16 + l15];
        float s = 0.0f;
        #pragma unroll
        for (int mt = 0; mt < 4; ++mt) {
            #pragma unroll
            for (int q = 0; q < 4; ++q) {
                const int row = mt * 16 + lhi * 4 + q;   // C/D: col=l15, row=4*lhi+q
                const float v = fmaxf(acc[mt][nt][q] + bb, 0.0f);
                s += (row < CTXL) ? v : 0.0f;
            }
        }
        s += __shfl_xor(s, 16);
        s += __shfl_xor(s, 32);
        if (lhi == 0) pooled[wave * 64 + nt * 16 + l15] = s * (1.0f / CTXL);
    }
    __syncthreads();

    // -------- phase 3: gate = sigmoid(pooled @ W2 + b2); out = gate*xemb ----
    for (int j = tid; j < NC; j += NT) {
        float s = b2[j];
        const s16x8* wrow = (const s16x8*)(W2T + (size_t)j * NH);
        #pragma unroll
        for (int c = 0; c < NH / 8; ++c) {
            const s16x8 w8 = wrow[c];
            const float4 p0 = *(const float4*)(&pooled[c * 8]);
            const float4 p1 = *(const float4*)(&pooled[c * 8 + 4]);
            s = fmaf(p0.x, bf2f((ushort)w8[0]), s);
            s = fmaf(p0.y, bf2f((ushort)w8[1]), s);
            s = fmaf(p0.z, bf2f((ushort)w8[2]), s);
            s = fmaf(p0.w, bf2f((ushort)w8[3]), s);
            s = fmaf(p1.x, bf2f((ushort)w8[4]), s);
            s = fmaf(p1.y, bf2f((ushort)w8[5]), s);
            s = fmaf(p1.z, bf2f((ushort)w8[6]), s);
            s = fmaf(p1.w, bf2f((ushort)w8[7]), s);
        }
        const float g = 1.0f / (1.0f + __expf(-s));
        out[(size_t)b * NC + j] = g * xemb[j];
    }
}

extern "C" void kernel_launch(void* const* d_in, const int* in_sizes, int n_in,
                              void* d_out, int out_size, void* d_ws, size_t ws_size,
                              hipStream_t stream) {
    const int*   x    = (const int*)d_in[0];
    const int*   ctx  = (const int*)d_in[1];
    const float* embs = (const float*)d_in[2];
    const float* W1   = (const float*)d_in[3];
    const float* b1   = (const float*)d_in[4];
    const float* W2   = (const float*)d_in[5];
    const float* b2   = (const float*)d_in[6];
    float* out = (float*)d_out;

    const int B    = in_sizes[0];
    const int ntok = in_sizes[2] / NC;

    const size_t w1t_bytes = (size_t)NH * KPAD * 2;   // 163840
    const size_t w2t_bytes = (size_t)NC * NH * 2;     // 153600
    const size_t e16_bytes = (size_t)ntok * KPAD * 2; // 64 MB

    if (ws_size >= e16_bytes + w1t_bytes + w2t_bytes) {
        // big-ws path: bf16 embedding table staged in workspace (L3-resident)
        ushort* E16 = (ushort*)d_ws;
        ushort* W1T = (ushort*)((char*)d_ws + e16_bytes);
        ushort* W2T = (ushort*)((char*)d_ws + e16_bytes + w1t_bytes);
        const int total  = ntok * 40;
        const int cblks  = min(2048, (total + NT - 1) / NT);
        convert_table<<<cblks, NT, 0, stream>>>(embs, E16, ntok);
        convert_w<<<KPAD + NC, NT, 0, stream>>>(W1, W2, W1T, W2T);
        esa_main<true><<<B, NT, 0, stream>>>(x, ctx, embs, b1, b2, E16, W1T, W2T, out);
    } else {
        // small-ws path: weights only in workspace, gather converts on the fly
        ushort* W1T = (ushort*)d_ws;
        ushort* W2T = (ushort*)((char*)d_ws + w1t_bytes);
        convert_w<<<KPAD + NC, NT, 0, stream>>>(W1, W2, W1T, W2T);
        esa_main<false><<<B, NT, 0, stream>>>(x, ctx, embs, b1, b2, nullptr, W1T, W2T, out);
    }
}